// Round 1
// baseline (2072.122 us; speedup 1.0000x reference)
//
#include <hip/hip_runtime.h>

// ---------------------------------------------------------------------------
// MultiviewSNF: 3x (x@w1 -> spmm -> +b,relu -> @w2 -> spmm -> +b) -> fusion -> q
// N=50000 nodes, E=800000 edges/view, HID=128, EMB=64, K=10
// ---------------------------------------------------------------------------

#define N_NODES 50000
#define N_EDGES 800000
#define HID 128
#define EMB 64
#define NCLU 10

using bf16x8 = __attribute__((ext_vector_type(8))) short;
using f32x4  = __attribute__((ext_vector_type(4))) float;

static __device__ __forceinline__ unsigned short f2bf(float f) {
    unsigned int u = __float_as_uint(f);
    unsigned int r = (u + 0x7FFF + ((u >> 16) & 1)) >> 16;  // RNE
    return (unsigned short)r;
}

// ---------------- CSR build ----------------

__global__ void hist_kernel(const int* __restrict__ rows, int* __restrict__ counts, int E) {
    int t = blockIdx.x * 256 + threadIdx.x;
    if (t < E) atomicAdd(&counts[rows[t]], 1);
}

// single-block hierarchical exclusive scan: counts[N] -> row_ptr[N+1], cursor[N]
__global__ void scan_kernel(const int* __restrict__ counts, int* __restrict__ row_ptr,
                            int* __restrict__ cursor, int n) {
    __shared__ int wt[16];
    int tid = threadIdx.x;
    int lane = tid & 63, wid = tid >> 6;
    int base = 0;
    const int CH = 1024 * 4;
    for (int start = 0; start < n; start += CH) {
        int i0 = start + tid * 4;
        int v0 = (i0 + 0 < n) ? counts[i0 + 0] : 0;
        int v1 = (i0 + 1 < n) ? counts[i0 + 1] : 0;
        int v2 = (i0 + 2 < n) ? counts[i0 + 2] : 0;
        int v3 = (i0 + 3 < n) ? counts[i0 + 3] : 0;
        int s = v0 + v1 + v2 + v3;
        int incl = s;
        #pragma unroll
        for (int d = 1; d < 64; d <<= 1) {
            int u = __shfl_up(incl, d, 64);
            if (lane >= d) incl += u;
        }
        if (lane == 63) wt[wid] = incl;
        __syncthreads();
        if (wid == 0) {
            int t2 = (lane < 16) ? wt[lane] : 0;
            #pragma unroll
            for (int d = 1; d < 16; d <<= 1) {
                int u = __shfl_up(t2, d, 64);
                if (lane >= d) t2 += u;
            }
            if (lane < 16) wt[lane] = t2;
        }
        __syncthreads();
        int woff = (wid == 0) ? 0 : wt[wid - 1];
        int total = wt[15];
        int e0 = base + woff + (incl - s);
        int e1 = e0 + v0, e2 = e1 + v1, e3 = e2 + v2;
        if (i0 + 0 < n) { row_ptr[i0 + 0] = e0; cursor[i0 + 0] = e0; }
        if (i0 + 1 < n) { row_ptr[i0 + 1] = e1; cursor[i0 + 1] = e1; }
        if (i0 + 2 < n) { row_ptr[i0 + 2] = e2; cursor[i0 + 2] = e2; }
        if (i0 + 3 < n) { row_ptr[i0 + 3] = e3; cursor[i0 + 3] = e3; }
        base += total;
        __syncthreads();
    }
    if (tid == 0) row_ptr[n] = base;
}

__global__ void scatter_kernel(const int* __restrict__ rows, int* __restrict__ cursor,
                               int* __restrict__ perm, int E) {
    int t = blockIdx.x * 256 + threadIdx.x;
    if (t < E) {
        int r = rows[t];
        int p = atomicAdd(&cursor[r], 1);
        perm[p] = t;
    }
}

// ---------------- weight convert: w1[din][128] fp32 -> w1t[128][dinp] bf16 (zero-padded K) ----

__global__ void wconv_kernel(const float* __restrict__ w, unsigned short* __restrict__ wt,
                             int din, int dinp) {
    int t = blockIdx.x * 256 + threadIdx.x;
    if (t >= 128 * dinp) return;
    int n = t / dinp, k = t - n * dinp;
    float f = (k < din) ? w[(size_t)k * 128 + n] : 0.f;
    wt[(size_t)n * dinp + k] = f2bf(f);
}

// ---------------- GEMM1: xw[N][128] = x[N][din] @ w1 (bf16 MFMA) ----------------
// 128x128 tile, 4 waves of 64x64, BK=32, mfma_f32_16x16x32_bf16

#define SA 40  // A LDS row stride (elements); 80B = 5*16B keeps b128 alignment, breaks bank conflicts

__global__ __launch_bounds__(256) void gemm1_kernel(
    const float* __restrict__ x, const unsigned short* __restrict__ w1t,
    float* __restrict__ xw, int Nn, int din, int dinp)
{
    __shared__ unsigned short As[128 * SA];
    __shared__ unsigned short Bs[128 * 32];
    int tid = threadIdx.x;
    int lane = tid & 63, wid = tid >> 6;
    int wm = wid & 1, wn = wid >> 1;
    int row0 = blockIdx.x * 128;
    f32x4 acc[4][4] = {};
    int numK = dinp >> 5;
    int sa_k = (tid & 7) * 4;   // 0..28
    int sa_r = tid >> 3;        // 0..31
    for (int kt = 0; kt < numK; ++kt) {
        int k0 = kt << 5;
        __syncthreads();
        // stage A (fp32 -> bf16), 4 passes of 32 rows, zero-pad OOB rows / K-tail
        #pragma unroll
        for (int p = 0; p < 4; ++p) {
            int r = sa_r + p * 32;
            int gr = row0 + r;
            float4 v = make_float4(0.f, 0.f, 0.f, 0.f);
            if (gr < Nn && (k0 + sa_k) < din)
                v = *(const float4*)(x + (size_t)gr * din + k0 + sa_k);
            ushort4 b;
            b.x = f2bf(v.x); b.y = f2bf(v.y); b.z = f2bf(v.z); b.w = f2bf(v.w);
            *(ushort4*)(&As[r * SA + sa_k]) = b;
        }
        // stage B from pre-transposed bf16 w1t[n][k]; pad region pre-zeroed
        #pragma unroll
        for (int p = 0; p < 2; ++p) {
            int idx = p * 256 + tid;
            int n = idx >> 2, quad = idx & 3;
            bf16x8 t = *(const bf16x8*)(w1t + (size_t)n * dinp + k0 + quad * 8);
            *(bf16x8*)(&Bs[n * 32 + quad * 8]) = t;
        }
        __syncthreads();
        int kq = (lane >> 4) * 8;
        int sub = lane & 15;
        bf16x8 af[4], bfr[4];
        #pragma unroll
        for (int mt = 0; mt < 4; ++mt)
            af[mt] = *(const bf16x8*)(&As[(wm * 64 + mt * 16 + sub) * SA + kq]);
        #pragma unroll
        for (int nt = 0; nt < 4; ++nt)
            bfr[nt] = *(const bf16x8*)(&Bs[(wn * 64 + nt * 16 + sub) * 32 + kq]);
        #pragma unroll
        for (int mt = 0; mt < 4; ++mt)
            #pragma unroll
            for (int nt = 0; nt < 4; ++nt)
                acc[mt][nt] = __builtin_amdgcn_mfma_f32_16x16x32_bf16(af[mt], bfr[nt], acc[mt][nt], 0, 0, 0);
    }
    // C layout: col = lane&15, row = (lane>>4)*4 + reg
    #pragma unroll
    for (int mt = 0; mt < 4; ++mt) {
        #pragma unroll
        for (int nt = 0; nt < 4; ++nt) {
            int col = wn * 64 + nt * 16 + (lane & 15);
            #pragma unroll
            for (int r = 0; r < 4; ++r) {
                int row = row0 + wm * 64 + mt * 16 + (lane >> 4) * 4 + r;
                if (row < Nn) xw[(size_t)row * 128 + col] = acc[mt][nt][r];
            }
        }
    }
}

// ---------------- SpMM (gather over CSR perm), F=128 with bias+relu ----------------

__global__ __launch_bounds__(256) void spmm128_kernel(
    const float* __restrict__ src, const int* __restrict__ row_ptr,
    const int* __restrict__ perm, const int* __restrict__ cols,
    const float* __restrict__ vals, const float* __restrict__ bias,
    float* __restrict__ dst)
{
    int lane = threadIdx.x & 63;
    int r = blockIdx.x * 4 + (threadIdx.x >> 6);
    int s = row_ptr[r], e = row_ptr[r + 1];
    int f = lane * 2;
    float a0 = 0.f, a1 = 0.f;
    for (int j = s; j < e; ++j) {
        int ed = perm[j];
        int c = cols[ed];
        float v = vals[ed];
        float2 t = *(const float2*)(src + (size_t)c * 128 + f);
        a0 += v * t.x; a1 += v * t.y;
    }
    a0 += bias[f]; a1 += bias[f + 1];
    a0 = fmaxf(a0, 0.f); a1 = fmaxf(a1, 0.f);
    float2 o; o.x = a0; o.y = a1;
    *(float2*)(dst + (size_t)r * 128 + f) = o;
}

// F=64, bias, no relu
__global__ __launch_bounds__(256) void spmm64_kernel(
    const float* __restrict__ src, const int* __restrict__ row_ptr,
    const int* __restrict__ perm, const int* __restrict__ cols,
    const float* __restrict__ vals, const float* __restrict__ bias,
    float* __restrict__ dst)
{
    int lane = threadIdx.x & 63;
    int r = blockIdx.x * 4 + (threadIdx.x >> 6);
    int s = row_ptr[r], e = row_ptr[r + 1];
    float a = 0.f;
    for (int j = s; j < e; ++j) {
        int ed = perm[j];
        int c = cols[ed];
        float v = vals[ed];
        a += v * src[(size_t)c * 64 + lane];
    }
    dst[(size_t)r * 64 + lane] = a + bias[lane];
}

// ---------------- GEMM2: hw[N][64] = h[N][128] @ w2[128][64] (fp32, LDS weights) --------

__global__ __launch_bounds__(256) void gemm2_kernel(
    const float* __restrict__ h, const float* __restrict__ w2, float* __restrict__ hw)
{
    __shared__ float w2s[128 * 64];
    int tid = threadIdx.x;
    for (int i = tid; i < 128 * 64; i += 256) w2s[i] = w2[i];
    __syncthreads();
    int n = tid & 63, g = tid >> 6;
    int r0 = blockIdx.x * 16 + g * 4;
    const float* h0 = h + (size_t)r0 * 128;
    float a0 = 0.f, a1 = 0.f, a2 = 0.f, a3 = 0.f;
    #pragma unroll 4
    for (int k = 0; k < 128; ++k) {
        float w = w2s[k * 64 + n];
        a0 += h0[k] * w;
        a1 += h0[128 + k] * w;
        a2 += h0[256 + k] * w;
        a3 += h0[384 + k] * w;
    }
    hw[(size_t)(r0 + 0) * 64 + n] = a0;
    hw[(size_t)(r0 + 1) * 64 + n] = a1;
    hw[(size_t)(r0 + 2) * 64 + n] = a2;
    hw[(size_t)(r0 + 3) * 64 + n] = a3;
}

// ---------------- fusion: z_fused = relu(concat(z0,z1,z2) @ fw + fb) ----------------

__global__ __launch_bounds__(256) void fusion_kernel(
    const float* __restrict__ z, const float* __restrict__ fw,
    const float* __restrict__ fb, float* __restrict__ zf)
{
    __shared__ float ws_[192 * 64];  // 48 KB
    int tid = threadIdx.x;
    for (int i = tid; i < 192 * 64; i += 256) ws_[i] = fw[i];
    __syncthreads();
    int n = tid & 63, g = tid >> 6;
    int r0 = blockIdx.x * 16 + g * 4;
    float a0 = 0.f, a1 = 0.f, a2 = 0.f, a3 = 0.f;
    #pragma unroll
    for (int v = 0; v < 3; ++v) {
        const float* zv = z + (size_t)v * N_NODES * 64;
        const float* z0 = zv + (size_t)(r0 + 0) * 64;
        const float* z1 = zv + (size_t)(r0 + 1) * 64;
        const float* z2 = zv + (size_t)(r0 + 2) * 64;
        const float* z3 = zv + (size_t)(r0 + 3) * 64;
        #pragma unroll 4
        for (int k = 0; k < 64; ++k) {
            float w = ws_[(v * 64 + k) * 64 + n];
            a0 += z0[k] * w; a1 += z1[k] * w; a2 += z2[k] * w; a3 += z3[k] * w;
        }
    }
    float b = fb[n];
    zf[(size_t)(r0 + 0) * 64 + n] = fmaxf(a0 + b, 0.f);
    zf[(size_t)(r0 + 1) * 64 + n] = fmaxf(a1 + b, 0.f);
    zf[(size_t)(r0 + 2) * 64 + n] = fmaxf(a2 + b, 0.f);
    zf[(size_t)(r0 + 3) * 64 + n] = fmaxf(a3 + b, 0.f);
}

// ---------------- q: Student-t soft assignment ----------------

__global__ __launch_bounds__(256) void q_kernel(
    const float* __restrict__ zf, const float* __restrict__ cluster, float* __restrict__ q)
{
    int lane = threadIdx.x & 63;
    int r = blockIdx.x * 4 + (threadIdx.x >> 6);
    float zl = zf[(size_t)r * 64 + lane];
    float d2[NCLU];
    #pragma unroll
    for (int k = 0; k < NCLU; ++k) {
        float d = zl - cluster[k * 64 + lane];
        float s = d * d;
        #pragma unroll
        for (int m = 32; m; m >>= 1) s += __shfl_xor(s, m, 64);
        d2[k] = s;
    }
    float S = 0.f;
    #pragma unroll
    for (int k = 0; k < NCLU; ++k) S += 1.f / (1.f + d2[k]);
    float myq = 0.f;
    #pragma unroll
    for (int k = 0; k < NCLU; ++k)
        if (lane == k) myq = 1.f / (1.f + d2[k]);
    if (lane < NCLU) q[(size_t)r * NCLU + lane] = myq / S;
}

// ---------------- launch ----------------

extern "C" void kernel_launch(void* const* d_in, const int* in_sizes, int n_in,
                              void* d_out, int out_size, void* d_ws, size_t ws_size,
                              hipStream_t stream)
{
    const int N = N_NODES, E = N_EDGES;
    static const int dins[3] = {1000, 800, 600};
    float* out = (float*)d_out;
    char* base = (char*)d_ws;
    size_t off = 0;
    auto alloc = [&](size_t bytes) -> void* {
        void* p = base + off;
        off = (off + bytes + 255) & ~(size_t)255;
        return p;
    };
    float* xw = (float*)alloc((size_t)N * 128 * 4);
    float* h  = (float*)alloc((size_t)N * 128 * 4);
    float* hw = (float*)alloc((size_t)N * 64 * 4);
    unsigned short* w1t = (unsigned short*)alloc(128 * 1024 * 2);
    int* counts  = (int*)alloc((size_t)N * 4);
    int* cursor  = (int*)alloc((size_t)N * 4);
    int* row_ptr = (int*)alloc((size_t)(N + 1) * 4);
    int* perm    = (int*)alloc((size_t)E * 4);

    for (int v = 0; v < 3; ++v) {
        const float* x    = (const float*)d_in[8 * v + 0];
        const int*   rows = (const int*)  d_in[8 * v + 1];
        const int*   cols = (const int*)  d_in[8 * v + 2];
        const float* vals = (const float*)d_in[8 * v + 3];
        const float* w1   = (const float*)d_in[8 * v + 4];
        const float* b1   = (const float*)d_in[8 * v + 5];
        const float* w2   = (const float*)d_in[8 * v + 6];
        const float* b2   = (const float*)d_in[8 * v + 7];
        int din = dins[v], dinp = (din + 31) & ~31;

        hipMemsetAsync(counts, 0, (size_t)N * 4, stream);
        hist_kernel<<<E / 256, 256, 0, stream>>>(rows, counts, E);
        scan_kernel<<<1, 1024, 0, stream>>>(counts, row_ptr, cursor, N);
        scatter_kernel<<<E / 256, 256, 0, stream>>>(rows, cursor, perm, E);
        wconv_kernel<<<(128 * dinp + 255) / 256, 256, 0, stream>>>(w1, w1t, din, dinp);
        gemm1_kernel<<<(N + 127) / 128, 256, 0, stream>>>(x, w1t, xw, N, din, dinp);
        spmm128_kernel<<<N / 4, 256, 0, stream>>>(xw, row_ptr, perm, cols, vals, b1, h);
        gemm2_kernel<<<N / 16, 256, 0, stream>>>(h, w2, hw);
        spmm64_kernel<<<N / 4, 256, 0, stream>>>(hw, row_ptr, perm, cols, vals, b2,
                                                 out + (size_t)v * N * 64);
    }
    const float* fw = (const float*)d_in[24];
    const float* fb = (const float*)d_in[25];
    const float* cl = (const float*)d_in[26];
    fusion_kernel<<<N / 16, 256, 0, stream>>>(out, fw, fb, out + (size_t)3 * N * 64);
    q_kernel<<<N / 4, 256, 0, stream>>>(out + (size_t)3 * N * 64, cl, out + (size_t)4 * N * 64);
}

// Round 2
// 1339.059 us; speedup vs baseline: 1.5474x; 1.5474x over previous
//
#include <hip/hip_runtime.h>

// ---------------------------------------------------------------------------
// MultiviewSNF: 3x (x@w1 -> spmm -> +b,relu -> @w2 -> spmm -> +b) -> fusion -> q
// N=50000 nodes, E=800000 edges/view, HID=128, EMB=64, K=10
// Round 2: bf16 intermediates (halve gather traffic), sorted (col,val) pairs
// (no perm indirection), multi-block scan, unrolled spmm.
// ---------------------------------------------------------------------------

#define N_NODES 50000
#define N_EDGES 800000
#define HID 128
#define EMB 64
#define NCLU 10

using bf16x8 = __attribute__((ext_vector_type(8))) short;
using f32x4  = __attribute__((ext_vector_type(4))) float;

static __device__ __forceinline__ unsigned short f2bf(float f) {
    unsigned int u = __float_as_uint(f);
    unsigned int r = (u + 0x7FFF + ((u >> 16) & 1)) >> 16;  // RNE
    return (unsigned short)r;
}
static __device__ __forceinline__ float bflo(unsigned int t) {
    return __uint_as_float(t << 16);
}
static __device__ __forceinline__ float bfhi(unsigned int t) {
    return __uint_as_float(t & 0xFFFF0000u);
}

// ---------------- CSR build ----------------

__global__ void hist_kernel(const int* __restrict__ rows, int* __restrict__ counts, int E) {
    int t = blockIdx.x * 256 + threadIdx.x;
    if (t < E) atomicAdd(&counts[rows[t]], 1);
}

// block-local exclusive scan of 256 counts; tmp = local excl prefix, bsum = block total
__global__ __launch_bounds__(256) void scan1_kernel(
    const int* __restrict__ counts, int* __restrict__ tmp, int* __restrict__ bsum, int n)
{
    __shared__ int wt[4];
    int t = threadIdx.x, b = blockIdx.x;
    int i = b * 256 + t;
    int lane = t & 63, wid = t >> 6;
    int v = (i < n) ? counts[i] : 0;
    int incl = v;
    #pragma unroll
    for (int d = 1; d < 64; d <<= 1) {
        int u = __shfl_up(incl, d, 64);
        if (lane >= d) incl += u;
    }
    if (lane == 63) wt[wid] = incl;
    __syncthreads();
    int woff = 0;
    #pragma unroll
    for (int w = 0; w < 4; ++w) if (w < wid) woff += wt[w];
    if (i < n) tmp[i] = woff + incl - v;
    if (t == 255) bsum[b] = woff + incl;
}

// single block: exclusive scan of nb (<=256) block sums; also writes row_ptr[n] = total
__global__ __launch_bounds__(256) void scan2_kernel(
    const int* __restrict__ bsum, int* __restrict__ boff, int nb,
    int* __restrict__ row_ptr, int n)
{
    __shared__ int wt[4];
    int t = threadIdx.x;
    int lane = t & 63, wid = t >> 6;
    int v = (t < nb) ? bsum[t] : 0;
    int incl = v;
    #pragma unroll
    for (int d = 1; d < 64; d <<= 1) {
        int u = __shfl_up(incl, d, 64);
        if (lane >= d) incl += u;
    }
    if (lane == 63) wt[wid] = incl;
    __syncthreads();
    int woff = 0;
    #pragma unroll
    for (int w = 0; w < 4; ++w) if (w < wid) woff += wt[w];
    if (t < nb) boff[t] = woff + incl - v;
    if (t == nb - 1) row_ptr[n] = woff + incl;
}

__global__ __launch_bounds__(256) void scan3_kernel(
    const int* __restrict__ tmp, const int* __restrict__ boff,
    int* __restrict__ row_ptr, int* __restrict__ cursor, int n)
{
    int i = blockIdx.x * 256 + threadIdx.x;
    if (i < n) {
        int e = tmp[i] + boff[blockIdx.x];
        row_ptr[i] = e;
        cursor[i] = e;
    }
}

// scatter edges into CSR order as packed (col:int-bits, val:float) pairs
__global__ void scatter_kernel(const int* __restrict__ rows, const int* __restrict__ cols,
                               const float* __restrict__ vals, int* __restrict__ cursor,
                               float2* __restrict__ cv, int E) {
    int t = blockIdx.x * 256 + threadIdx.x;
    if (t < E) {
        int r = rows[t];
        int p = atomicAdd(&cursor[r], 1);
        float2 e;
        e.x = __uint_as_float((unsigned int)cols[t]);
        e.y = vals[t];
        cv[p] = e;
    }
}

// ---------------- weight convert: w1[din][128] fp32 -> w1t[128][dinp] bf16 (zero-padded K) ----

__global__ void wconv_kernel(const float* __restrict__ w, unsigned short* __restrict__ wt,
                             int din, int dinp) {
    int t = blockIdx.x * 256 + threadIdx.x;
    if (t >= 128 * dinp) return;
    int n = t / dinp, k = t - n * dinp;
    float f = (k < din) ? w[(size_t)k * 128 + n] : 0.f;
    wt[(size_t)n * dinp + k] = f2bf(f);
}

// ---------------- GEMM1: xw[N][128] (bf16) = x[N][din] @ w1 (bf16 MFMA) ----------------
// 128x128 tile, 4 waves of 64x64, BK=32, mfma_f32_16x16x32_bf16

#define SA 40  // A LDS row stride (elements); 80B keeps 16B alignment, breaks bank conflicts

__global__ __launch_bounds__(256) void gemm1_kernel(
    const float* __restrict__ x, const unsigned short* __restrict__ w1t,
    unsigned short* __restrict__ xw, int Nn, int din, int dinp)
{
    __shared__ unsigned short As[128 * SA];
    __shared__ unsigned short Bs[128 * 32];
    int tid = threadIdx.x;
    int lane = tid & 63, wid = tid >> 6;
    int wm = wid & 1, wn = wid >> 1;
    int row0 = blockIdx.x * 128;
    f32x4 acc[4][4] = {};
    int numK = dinp >> 5;
    int sa_k = (tid & 7) * 4;   // 0..28
    int sa_r = tid >> 3;        // 0..31
    for (int kt = 0; kt < numK; ++kt) {
        int k0 = kt << 5;
        __syncthreads();
        #pragma unroll
        for (int p = 0; p < 4; ++p) {
            int r = sa_r + p * 32;
            int gr = row0 + r;
            float4 v = make_float4(0.f, 0.f, 0.f, 0.f);
            if (gr < Nn && (k0 + sa_k) < din)
                v = *(const float4*)(x + (size_t)gr * din + k0 + sa_k);
            ushort4 b;
            b.x = f2bf(v.x); b.y = f2bf(v.y); b.z = f2bf(v.z); b.w = f2bf(v.w);
            *(ushort4*)(&As[r * SA + sa_k]) = b;
        }
        #pragma unroll
        for (int p = 0; p < 2; ++p) {
            int idx = p * 256 + tid;
            int n = idx >> 2, quad = idx & 3;
            bf16x8 t = *(const bf16x8*)(w1t + (size_t)n * dinp + k0 + quad * 8);
            *(bf16x8*)(&Bs[n * 32 + quad * 8]) = t;
        }
        __syncthreads();
        int kq = (lane >> 4) * 8;
        int sub = lane & 15;
        bf16x8 af[4], bfr[4];
        #pragma unroll
        for (int mt = 0; mt < 4; ++mt)
            af[mt] = *(const bf16x8*)(&As[(wm * 64 + mt * 16 + sub) * SA + kq]);
        #pragma unroll
        for (int nt = 0; nt < 4; ++nt)
            bfr[nt] = *(const bf16x8*)(&Bs[(wn * 64 + nt * 16 + sub) * 32 + kq]);
        #pragma unroll
        for (int mt = 0; mt < 4; ++mt)
            #pragma unroll
            for (int nt = 0; nt < 4; ++nt)
                acc[mt][nt] = __builtin_amdgcn_mfma_f32_16x16x32_bf16(af[mt], bfr[nt], acc[mt][nt], 0, 0, 0);
    }
    // C layout: col = lane&15, row = (lane>>4)*4 + reg
    #pragma unroll
    for (int mt = 0; mt < 4; ++mt) {
        #pragma unroll
        for (int nt = 0; nt < 4; ++nt) {
            int col = wn * 64 + nt * 16 + (lane & 15);
            #pragma unroll
            for (int r = 0; r < 4; ++r) {
                int row = row0 + wm * 64 + mt * 16 + (lane >> 4) * 4 + r;
                if (row < Nn) xw[(size_t)row * 128 + col] = f2bf(acc[mt][nt][r]);
            }
        }
    }
}

// ---------------- SpMM F=128 (bf16 src), bias+relu, bf16 dst ----------------
// wave per row; lane covers features {2*lane, 2*lane+1} via one uint load

__global__ __launch_bounds__(256) void spmm128_kernel(
    const unsigned short* __restrict__ src, const int* __restrict__ row_ptr,
    const float2* __restrict__ cv, const float* __restrict__ bias,
    unsigned short* __restrict__ dst)
{
    const unsigned int* srcu = (const unsigned int*)src;
    int lane = threadIdx.x & 63;
    int r = blockIdx.x * 4 + (threadIdx.x >> 6);
    int s = row_ptr[r], e = row_ptr[r + 1];
    float a0 = 0.f, a1 = 0.f, b0 = 0.f, b1 = 0.f;
    int j = s;
    for (; j + 4 <= e; j += 4) {
        float2 p0 = cv[j], p1 = cv[j + 1], p2 = cv[j + 2], p3 = cv[j + 3];
        unsigned int t0 = srcu[(size_t)__float_as_uint(p0.x) * 64 + lane];
        unsigned int t1 = srcu[(size_t)__float_as_uint(p1.x) * 64 + lane];
        unsigned int t2 = srcu[(size_t)__float_as_uint(p2.x) * 64 + lane];
        unsigned int t3 = srcu[(size_t)__float_as_uint(p3.x) * 64 + lane];
        a0 += p0.y * bflo(t0); a1 += p0.y * bfhi(t0);
        b0 += p1.y * bflo(t1); b1 += p1.y * bfhi(t1);
        a0 += p2.y * bflo(t2); a1 += p2.y * bfhi(t2);
        b0 += p3.y * bflo(t3); b1 += p3.y * bfhi(t3);
    }
    for (; j < e; ++j) {
        float2 p = cv[j];
        unsigned int t = srcu[(size_t)__float_as_uint(p.x) * 64 + lane];
        a0 += p.y * bflo(t); a1 += p.y * bfhi(t);
    }
    a0 += b0 + bias[lane * 2];
    a1 += b1 + bias[lane * 2 + 1];
    a0 = fmaxf(a0, 0.f); a1 = fmaxf(a1, 0.f);
    unsigned int o = (unsigned int)f2bf(a0) | ((unsigned int)f2bf(a1) << 16);
    ((unsigned int*)dst)[(size_t)r * 64 + lane] = o;
}

// ---------------- SpMM F=64 (bf16 src), +bias, fp32 dst ----------------

__global__ __launch_bounds__(256) void spmm64_kernel(
    const unsigned short* __restrict__ src, const int* __restrict__ row_ptr,
    const float2* __restrict__ cv, const float* __restrict__ bias,
    float* __restrict__ dst)
{
    int lane = threadIdx.x & 63;
    int r = blockIdx.x * 4 + (threadIdx.x >> 6);
    int s = row_ptr[r], e = row_ptr[r + 1];
    float a0 = 0.f, b0 = 0.f;
    int j = s;
    for (; j + 4 <= e; j += 4) {
        float2 p0 = cv[j], p1 = cv[j + 1], p2 = cv[j + 2], p3 = cv[j + 3];
        float f0 = __uint_as_float((unsigned int)src[(size_t)__float_as_uint(p0.x) * 64 + lane] << 16);
        float f1 = __uint_as_float((unsigned int)src[(size_t)__float_as_uint(p1.x) * 64 + lane] << 16);
        float f2 = __uint_as_float((unsigned int)src[(size_t)__float_as_uint(p2.x) * 64 + lane] << 16);
        float f3 = __uint_as_float((unsigned int)src[(size_t)__float_as_uint(p3.x) * 64 + lane] << 16);
        a0 += p0.y * f0; b0 += p1.y * f1;
        a0 += p2.y * f2; b0 += p3.y * f3;
    }
    for (; j < e; ++j) {
        float2 p = cv[j];
        float f = __uint_as_float((unsigned int)src[(size_t)__float_as_uint(p.x) * 64 + lane] << 16);
        a0 += p.y * f;
    }
    dst[(size_t)r * 64 + lane] = a0 + b0 + bias[lane];
}

// ---------------- GEMM2: hw[N][64] (bf16) = h[N][128] (bf16) @ w2[128][64] (fp32 LDS) ----

__global__ __launch_bounds__(256) void gemm2_kernel(
    const unsigned short* __restrict__ h, const float* __restrict__ w2,
    unsigned short* __restrict__ hw)
{
    __shared__ float w2s[128 * 64];
    int tid = threadIdx.x;
    for (int i = tid; i < 128 * 64; i += 256) w2s[i] = w2[i];
    __syncthreads();
    int n = tid & 63, g = tid >> 6;
    int r0 = blockIdx.x * 16 + g * 4;
    const unsigned int* h0 = (const unsigned int*)(h + (size_t)r0 * 128);
    float a0 = 0.f, a1 = 0.f, a2 = 0.f, a3 = 0.f;
    #pragma unroll 4
    for (int k2 = 0; k2 < 64; ++k2) {
        unsigned int t0 = h0[k2], t1 = h0[64 + k2], t2 = h0[128 + k2], t3 = h0[192 + k2];
        float w0 = w2s[(2 * k2) * 64 + n];
        float w1 = w2s[(2 * k2 + 1) * 64 + n];
        a0 += bflo(t0) * w0 + bfhi(t0) * w1;
        a1 += bflo(t1) * w0 + bfhi(t1) * w1;
        a2 += bflo(t2) * w0 + bfhi(t2) * w1;
        a3 += bflo(t3) * w0 + bfhi(t3) * w1;
    }
    hw[(size_t)(r0 + 0) * 64 + n] = f2bf(a0);
    hw[(size_t)(r0 + 1) * 64 + n] = f2bf(a1);
    hw[(size_t)(r0 + 2) * 64 + n] = f2bf(a2);
    hw[(size_t)(r0 + 3) * 64 + n] = f2bf(a3);
}

// ---------------- fusion: z_fused = relu(concat(z0,z1,z2) @ fw + fb) ----------------

__global__ __launch_bounds__(256) void fusion_kernel(
    const float* __restrict__ z, const float* __restrict__ fw,
    const float* __restrict__ fb, float* __restrict__ zf)
{
    __shared__ float ws_[192 * 64];  // 48 KB
    int tid = threadIdx.x;
    for (int i = tid; i < 192 * 64; i += 256) ws_[i] = fw[i];
    __syncthreads();
    int n = tid & 63, g = tid >> 6;
    int r0 = blockIdx.x * 16 + g * 4;
    float a0 = 0.f, a1 = 0.f, a2 = 0.f, a3 = 0.f;
    #pragma unroll
    for (int v = 0; v < 3; ++v) {
        const float* zv = z + (size_t)v * N_NODES * 64;
        const float* z0 = zv + (size_t)(r0 + 0) * 64;
        const float* z1 = zv + (size_t)(r0 + 1) * 64;
        const float* z2 = zv + (size_t)(r0 + 2) * 64;
        const float* z3 = zv + (size_t)(r0 + 3) * 64;
        #pragma unroll 4
        for (int k = 0; k < 64; ++k) {
            float w = ws_[(v * 64 + k) * 64 + n];
            a0 += z0[k] * w; a1 += z1[k] * w; a2 += z2[k] * w; a3 += z3[k] * w;
        }
    }
    float b = fb[n];
    zf[(size_t)(r0 + 0) * 64 + n] = fmaxf(a0 + b, 0.f);
    zf[(size_t)(r0 + 1) * 64 + n] = fmaxf(a1 + b, 0.f);
    zf[(size_t)(r0 + 2) * 64 + n] = fmaxf(a2 + b, 0.f);
    zf[(size_t)(r0 + 3) * 64 + n] = fmaxf(a3 + b, 0.f);
}

// ---------------- q: Student-t soft assignment ----------------

__global__ __launch_bounds__(256) void q_kernel(
    const float* __restrict__ zf, const float* __restrict__ cluster, float* __restrict__ q)
{
    int lane = threadIdx.x & 63;
    int r = blockIdx.x * 4 + (threadIdx.x >> 6);
    float zl = zf[(size_t)r * 64 + lane];
    float d2[NCLU];
    #pragma unroll
    for (int k = 0; k < NCLU; ++k) {
        float d = zl - cluster[k * 64 + lane];
        float s = d * d;
        #pragma unroll
        for (int m = 32; m; m >>= 1) s += __shfl_xor(s, m, 64);
        d2[k] = s;
    }
    float S = 0.f;
    #pragma unroll
    for (int k = 0; k < NCLU; ++k) S += 1.f / (1.f + d2[k]);
    float myq = 0.f;
    #pragma unroll
    for (int k = 0; k < NCLU; ++k)
        if (lane == k) myq = 1.f / (1.f + d2[k]);
    if (lane < NCLU) q[(size_t)r * NCLU + lane] = myq / S;
}

// ---------------- launch ----------------

extern "C" void kernel_launch(void* const* d_in, const int* in_sizes, int n_in,
                              void* d_out, int out_size, void* d_ws, size_t ws_size,
                              hipStream_t stream)
{
    const int N = N_NODES, E = N_EDGES;
    const int NB = (N + 255) / 256;  // 196 scan blocks
    static const int dins[3] = {1000, 800, 600};
    float* out = (float*)d_out;
    char* base = (char*)d_ws;
    size_t off = 0;
    auto alloc = [&](size_t bytes) -> void* {
        void* p = base + off;
        off = (off + bytes + 255) & ~(size_t)255;
        return p;
    };
    unsigned short* xw = (unsigned short*)alloc((size_t)N * 128 * 2);
    unsigned short* h  = (unsigned short*)alloc((size_t)N * 128 * 2);
    unsigned short* hw = (unsigned short*)alloc((size_t)N * 64 * 2);
    unsigned short* w1t = (unsigned short*)alloc(128 * 1024 * 2);
    int* counts  = (int*)alloc((size_t)N * 4);
    int* cursor  = (int*)alloc((size_t)N * 4);
    int* row_ptr = (int*)alloc((size_t)(N + 1) * 4);
    int* tmp     = (int*)alloc((size_t)N * 4);
    int* bsum    = (int*)alloc((size_t)NB * 4);
    int* boff    = (int*)alloc((size_t)NB * 4);
    float2* cv   = (float2*)alloc((size_t)E * 8);

    for (int v = 0; v < 3; ++v) {
        const float* x    = (const float*)d_in[8 * v + 0];
        const int*   rows = (const int*)  d_in[8 * v + 1];
        const int*   cols = (const int*)  d_in[8 * v + 2];
        const float* vals = (const float*)d_in[8 * v + 3];
        const float* w1   = (const float*)d_in[8 * v + 4];
        const float* b1   = (const float*)d_in[8 * v + 5];
        const float* w2   = (const float*)d_in[8 * v + 6];
        const float* b2   = (const float*)d_in[8 * v + 7];
        int din = dins[v], dinp = (din + 31) & ~31;

        hipMemsetAsync(counts, 0, (size_t)N * 4, stream);
        hist_kernel<<<E / 256, 256, 0, stream>>>(rows, counts, E);
        scan1_kernel<<<NB, 256, 0, stream>>>(counts, tmp, bsum, N);
        scan2_kernel<<<1, 256, 0, stream>>>(bsum, boff, NB, row_ptr, N);
        scan3_kernel<<<NB, 256, 0, stream>>>(tmp, boff, row_ptr, cursor, N);
        scatter_kernel<<<E / 256, 256, 0, stream>>>(rows, cols, vals, cursor, cv, E);
        wconv_kernel<<<(128 * dinp + 255) / 256, 256, 0, stream>>>(w1, w1t, din, dinp);
        gemm1_kernel<<<(N + 127) / 128, 256, 0, stream>>>(x, w1t, xw, N, din, dinp);
        spmm128_kernel<<<N / 4, 256, 0, stream>>>(xw, row_ptr, cv, b1, h);
        gemm2_kernel<<<N / 16, 256, 0, stream>>>(h, w2, hw);
        spmm64_kernel<<<N / 4, 256, 0, stream>>>(hw, row_ptr, cv, b2,
                                                 out + (size_t)v * N * 64);
    }
    const float* fw = (const float*)d_in[24];
    const float* fb = (const float*)d_in[25];
    const float* cl = (const float*)d_in[26];
    fusion_kernel<<<N / 16, 256, 0, stream>>>(out, fw, fb, out + (size_t)3 * N * 64);
    q_kernel<<<N / 4, 256, 0, stream>>>(out + (size_t)3 * N * 64, cl, out + (size_t)4 * N * 64);
}